// Round 1
// baseline (509.639 us; speedup 1.0000x reference)
//
#include <hip/hip_runtime.h>
#include <math.h>

// TrueRingDilatedAttention on MI355X.
// Structure insight: gathered K/V (len 4096) = each of the 1024 local keys
// exactly 4 times (ring steps {0,2} cover even idx x2, {1,3} odd idx x2).
// So: softmax over 1024 distinct keys; denom = 4*S + EPS; out = 4*PV/denom.
//
// fp32 baseline (no fp32 MFMA on CDNA4): thread-per-query online softmax,
// q + O accumulator in VGPRs (float4), K/V tiles in LDS (broadcast reads).

constexpr int HEADS = 16;
constexpr int DIM   = 64;     // head dim
constexpr int NQ    = 4096;
constexpr int NK    = 1024;   // distinct keys
constexpr int KB    = 64;     // keys per LDS tile
constexpr int TPB   = 128;    // threads per block = queries per block
constexpr float SCALE = 0.125f;   // 1/sqrt(64)
constexpr float EPS   = 1e-8f;

__global__ __launch_bounds__(TPB)
void ring_attn_fp32(const float* __restrict__ q,
                    const float* __restrict__ k,
                    const float* __restrict__ v,
                    float* __restrict__ out)
{
    const int h   = blockIdx.y;
    const int qi  = blockIdx.x * TPB + threadIdx.x;
    const int tid = threadIdx.x;

    __shared__ float4 k4[KB][DIM / 4];
    __shared__ float4 v4[KB][DIM / 4];

    // q row -> registers (16 x float4)
    float4 q4[16];
    const float4* qptr =
        reinterpret_cast<const float4*>(q + (size_t)qi * (HEADS * DIM) + h * DIM);
    #pragma unroll
    for (int i = 0; i < 16; ++i) q4[i] = qptr[i];

    float4 o4[16];
    #pragma unroll
    for (int i = 0; i < 16; ++i) o4[i] = make_float4(0.f, 0.f, 0.f, 0.f);
    float m = -INFINITY;
    float l = 0.f;

    const float4* kg = reinterpret_cast<const float4*>(k);
    const float4* vg = reinterpret_cast<const float4*>(v);

    #pragma unroll 1
    for (int kt = 0; kt < NK; kt += KB) {
        __syncthreads();
        // stage K,V tile: KB rows x 16 float4. 128 threads -> 8 iters each.
        #pragma unroll
        for (int i = 0; i < (KB * 16) / TPB; ++i) {
            int idx = tid + i * TPB;
            int row = idx >> 4;          // key within tile
            int col = idx & 15;          // float4 within row
            size_t g = (size_t)(kt + row) * (HEADS * 16) + h * 16 + col;
            k4[row][col] = kg[g];
            v4[row][col] = vg[g];
        }
        __syncthreads();

        #pragma unroll 1
        for (int j0 = 0; j0 < KB; j0 += 16) {
            // scores for 16 keys
            float s[16];
            #pragma unroll
            for (int jj = 0; jj < 16; ++jj) {
                float4 a = make_float4(0.f, 0.f, 0.f, 0.f);
                #pragma unroll
                for (int d = 0; d < 16; ++d) {
                    float4 kk = k4[j0 + jj][d];   // wave-uniform broadcast
                    float4 qq = q4[d];
                    a.x += qq.x * kk.x; a.y += qq.y * kk.y;
                    a.z += qq.z * kk.z; a.w += qq.w * kk.w;
                }
                s[jj] = (a.x + a.y + a.z + a.w) * SCALE;
            }
            float mt = s[0];
            #pragma unroll
            for (int jj = 1; jj < 16; ++jj) mt = fmaxf(mt, s[jj]);
            float m_new = fmaxf(m, mt);
            if (m_new > m) {
                float alpha = __expf(m - m_new);   // m=-inf -> 0
                l *= alpha;
                #pragma unroll
                for (int i = 0; i < 16; ++i) {
                    o4[i].x *= alpha; o4[i].y *= alpha;
                    o4[i].z *= alpha; o4[i].w *= alpha;
                }
                m = m_new;
            }
            #pragma unroll
            for (int jj = 0; jj < 16; ++jj) {
                float p = __expf(s[jj] - m);
                l += p;
                #pragma unroll
                for (int d = 0; d < 16; ++d) {
                    float4 vv = v4[j0 + jj][d];   // wave-uniform broadcast
                    o4[d].x += p * vv.x; o4[d].y += p * vv.y;
                    o4[d].z += p * vv.z; o4[d].w += p * vv.w;
                }
            }
        }
    }

    // out = 4*PV / (4*S + EPS)
    float inv = 4.f / (4.f * l + EPS);
    float4* optr =
        reinterpret_cast<float4*>(out + (size_t)qi * (HEADS * DIM) + h * DIM);
    #pragma unroll
    for (int i = 0; i < 16; ++i) {
        float4 r = o4[i];
        r.x *= inv; r.y *= inv; r.z *= inv; r.w *= inv;
        optr[i] = r;
    }
}

extern "C" void kernel_launch(void* const* d_in, const int* in_sizes, int n_in,
                              void* d_out, int out_size, void* d_ws, size_t ws_size,
                              hipStream_t stream) {
    const float* q = (const float*)d_in[0];
    const float* k = (const float*)d_in[1];
    const float* v = (const float*)d_in[2];
    float* out = (float*)d_out;

    dim3 grid(NQ / TPB, HEADS);
    dim3 block(TPB);
    ring_attn_fp32<<<grid, block, 0, stream>>>(q, k, v, out);
}

// Round 3
// 81.887 us; speedup vs baseline: 6.2237x; 6.2237x over previous
//
#include <hip/hip_runtime.h>
#include <math.h>

// TrueRingDilatedAttention, MFMA version (R3: rescale-alpha fix).
// Math identity: gathered K/V (4096) = each of 1024 local keys exactly 4x
//   -> softmax over 1024 keys, denom = 4*S + EPS, out = 4*PV / denom.
// Numerics: Q,K split hi/lo bf16 (3-MFMA QK^T); P,V single bf16.
// Layout: swapped QK^T (A=K,B=Q^T). Lane's softmax state is per q=c (lane&15),
//   but o_acc rows are q'=4g+r (C/D row = 4*(lane>>4)+reg) -> the per-tile
//   rescale must use alpha shuffled from lane 4g+r (R2 bug: used own alpha).

typedef __attribute__((ext_vector_type(8))) short bf16x8;
typedef __attribute__((ext_vector_type(4))) float f32x4;

constexpr int HEADS = 16;
constexpr int NQ    = 4096;
constexpr int NK    = 1024;   // distinct keys
constexpr int KB    = 64;     // keys per tile
constexpr int TPB   = 256;    // 4 waves; each wave owns 16 q rows
constexpr float EPS = 1e-8f;

__device__ __forceinline__ ushort bf16_rn(float f) {
    uint u = __float_as_uint(f);
    u += 0x7FFF + ((u >> 16) & 1);
    return (ushort)(u >> 16);
}
__device__ __forceinline__ float bf16_f(ushort h) {
    return __uint_as_float(((uint)h) << 16);
}
// LDS rows of 128B, XOR-swizzled at 16B granularity
__device__ __forceinline__ int swz(int row, int byteInRow) {
    return row * 128 + (byteInRow ^ ((row & 7) << 4));
}

__global__ __launch_bounds__(TPB)
void ring_attn_mfma(const float* __restrict__ qg,
                    const float* __restrict__ kg,
                    const float* __restrict__ vg,
                    float* __restrict__ outg)
{
    __shared__ ushort Kh[64 * 64];   // K tile hi, [key][d]
    __shared__ ushort Kl[64 * 64];   // K tile lo
    __shared__ ushort Vt[64 * 64];   // V tile transposed, [d][key]
    __shared__ ushort Pl[4][16 * 64];// per-wave P, [q][key]

    const int h    = blockIdx.y;
    const int qblk = blockIdx.x;
    const int tid  = threadIdx.x;
    const int w    = tid >> 6;
    const int lane = tid & 63;
    const int g    = lane >> 4;
    const int c    = lane & 15;

    // ---- Q fragments (B operand of swapped QK^T): q col = c, d = cc*32+g*8+e
    // scale 1/8 folded here (exact power of 2)
    const int qi = qblk * 64 + w * 16 + c;
    bf16x8 qh[2], ql[2];
    {
        const float4* q4 = reinterpret_cast<const float4*>(qg);
        #pragma unroll
        for (int cc = 0; cc < 2; ++cc) {
            int base = (qi * 1024 + h * 64 + cc * 32 + g * 8) >> 2;
            float4 a = q4[base];
            float4 b = q4[base + 1];
            float vals[8] = {a.x, a.y, a.z, a.w, b.x, b.y, b.z, b.w};
            #pragma unroll
            for (int e = 0; e < 8; ++e) {
                float x = vals[e] * 0.125f;
                ushort hi = bf16_rn(x);
                qh[cc][e] = (short)hi;
                ql[cc][e] = (short)bf16_rn(x - bf16_f(hi));
            }
        }
    }

    f32x4 o_acc[4];
    #pragma unroll
    for (int t = 0; t < 4; ++t)
        #pragma unroll
        for (int r = 0; r < 4; ++r) o_acc[t][r] = 0.f;
    float m_run = -INFINITY;
    float l_run = 0.f;

    const float4* k4 = reinterpret_cast<const float4*>(kg);

    #pragma unroll 1
    for (int kt = 0; kt < NK / KB; ++kt) {
        const int kb = kt * KB;
        __syncthreads();
        // ---- stage K hi/lo: 64 keys x 64 d (row-major, swizzled)
        #pragma unroll
        for (int i = 0; i < 4; ++i) {
            int fi = i * 256 + tid;
            int j = fi >> 4, dq = fi & 15;
            float4 kv = k4[(kb + j) * 256 + h * 16 + dq];
            float kvals[4] = {kv.x, kv.y, kv.z, kv.w};
            ushort4 hi4, lo4;
            ushort* hp = (ushort*)&hi4; ushort* lp = (ushort*)&lo4;
            #pragma unroll
            for (int e = 0; e < 4; ++e) {
                ushort hh = bf16_rn(kvals[e]);
                hp[e] = hh;
                lp[e] = bf16_rn(kvals[e] - bf16_f(hh));
            }
            int addr = swz(j, dq * 8);
            *(ushort4*)((char*)Kh + addr) = hi4;
            *(ushort4*)((char*)Kl + addr) = lo4;
        }
        // ---- stage V transposed: Vt[d][j] (bf16)
        {
            int d  = tid & 63;
            int w4 = (tid >> 6) * 4;
            #pragma unroll
            for (int i = 0; i < 4; ++i) {
                int j0 = w4 + i * 16;
                ushort4 pv;
                ushort* pp = (ushort*)&pv;
                #pragma unroll
                for (int jj = 0; jj < 4; ++jj)
                    pp[jj] = bf16_rn(vg[(kb + j0 + jj) * 1024 + h * 64 + d]);
                *(ushort4*)((char*)Vt + swz(d, j0 * 2)) = pv;
            }
        }
        __syncthreads();

        // ---- swapped QK^T: S[key][q]; A=K rows, B=Q. 3 MFMAs per (t,cc).
        f32x4 s_acc[4];
        #pragma unroll
        for (int t = 0; t < 4; ++t)
            #pragma unroll
            for (int r = 0; r < 4; ++r) s_acc[t][r] = 0.f;
        #pragma unroll
        for (int t = 0; t < 4; ++t) {
            #pragma unroll
            for (int cc = 0; cc < 2; ++cc) {
                int row = 16 * t + c;
                bf16x8 ah = *(const bf16x8*)((const char*)Kh + swz(row, 64 * cc + 16 * g));
                bf16x8 al = *(const bf16x8*)((const char*)Kl + swz(row, 64 * cc + 16 * g));
                s_acc[t] = __builtin_amdgcn_mfma_f32_16x16x32_bf16(ah, qh[cc], s_acc[t], 0, 0, 0);
                s_acc[t] = __builtin_amdgcn_mfma_f32_16x16x32_bf16(al, qh[cc], s_acc[t], 0, 0, 0);
                s_acc[t] = __builtin_amdgcn_mfma_f32_16x16x32_bf16(ah, ql[cc], s_acc[t], 0, 0, 0);
            }
        }
        // lane holds S[key = kb+16t+4g+r][q = c]

        // ---- online softmax over this 64-key tile (per q = c)
        float tm = -INFINITY;
        #pragma unroll
        for (int t = 0; t < 4; ++t)
            #pragma unroll
            for (int r = 0; r < 4; ++r) tm = fmaxf(tm, s_acc[t][r]);
        tm = fmaxf(tm, __shfl_xor(tm, 16));
        tm = fmaxf(tm, __shfl_xor(tm, 32));
        float m_new = fmaxf(m_run, tm);
        float alpha = __expf(m_run - m_new);   // first tile: exp(-inf)=0
        m_run = m_new;

        float psum = 0.f;
        #pragma unroll
        for (int t = 0; t < 4; ++t) {
            ushort4 pk;
            ushort* pp = (ushort*)&pk;
            #pragma unroll
            for (int r = 0; r < 4; ++r) {
                float p = __expf(s_acc[t][r] - m_new);
                ushort pb = bf16_rn(p);
                pp[r] = pb;
                psum += bf16_f(pb);   // sum the rounded p for consistency
            }
            // keys 16t+4g..+3 for q=c -> byte 2*(16t+4g)
            *(ushort4*)((char*)(&Pl[w][0]) + swz(c, 32 * t + 8 * g)) = pk;
        }
        psum += __shfl_xor(psum, 16);
        psum += __shfl_xor(psum, 32);
        l_run = l_run * alpha + psum;

        // ---- rescale O: o_acc rows are q' = 4g+r -> need alpha of lane 4g+r
        {
            float a0 = __shfl(alpha, 4 * g + 0);
            float a1 = __shfl(alpha, 4 * g + 1);
            float a2 = __shfl(alpha, 4 * g + 2);
            float a3 = __shfl(alpha, 4 * g + 3);
            #pragma unroll
            for (int td = 0; td < 4; ++td) {
                o_acc[td][0] *= a0;
                o_acc[td][1] *= a1;
                o_acc[td][2] *= a2;
                o_acc[td][3] *= a3;
            }
        }

        // ---- PV: O[q][d] += P(16x64) * V(64x64); A=P from LDS, B=Vt
        #pragma unroll
        for (int cc = 0; cc < 2; ++cc) {
            bf16x8 pa = *(const bf16x8*)((const char*)(&Pl[w][0]) + swz(c, 64 * cc + 16 * g));
            #pragma unroll
            for (int td = 0; td < 4; ++td) {
                bf16x8 vb = *(const bf16x8*)((const char*)Vt + swz(16 * td + c, 64 * cc + 16 * g));
                o_acc[td] = __builtin_amdgcn_mfma_f32_16x16x32_bf16(pa, vb, o_acc[td], 0, 0, 0);
            }
        }
    }

    // ---- epilogue: lane's O rows are q' = 4g+r, cols d = 16td+c
    #pragma unroll
    for (int r = 0; r < 4; ++r) {
        float lq  = __shfl(l_run, 4 * g + r);     // l lives on lane (q', g=0)
        float inv = 4.f / (4.f * lq + EPS);
        int qrow  = qblk * 64 + w * 16 + 4 * g + r;
        #pragma unroll
        for (int td = 0; td < 4; ++td)
            outg[qrow * 1024 + h * 64 + 16 * td + c] = o_acc[td][r] * inv;
    }
}

extern "C" void kernel_launch(void* const* d_in, const int* in_sizes, int n_in,
                              void* d_out, int out_size, void* d_ws, size_t ws_size,
                              hipStream_t stream) {
    const float* q = (const float*)d_in[0];
    const float* k = (const float*)d_in[1];
    const float* v = (const float*)d_in[2];
    float* out = (float*)d_out;

    dim3 grid(NQ / 64, HEADS);
    dim3 block(TPB);
    ring_attn_mfma<<<grid, block, 0, stream>>>(q, k, v, out);
}

// Round 4
// 59.642 us; speedup vs baseline: 8.5449x; 1.3730x over previous
//
#include <hip/hip_runtime.h>
#include <math.h>

// TrueRingDilatedAttention R4.
// Identity: gathered K/V = each of 1024 local keys exactly 4x
//   -> softmax over 1024 keys, denom = 4*S + EPS, out = 4*PV/denom.
// R4: (1) pre-pass converts K (bf16 hi/lo, swizzled LDS image) + V (PV B-frag
// stream) into d_ws once per (head,tile); (2) main kernel: 32 q/wave, K via
// global_load_lds, V frags straight to registers; P round-trips wave-private
// LDS. QK^T swapped (A=K, B=Q) with 3-MFMA split-bf16.

typedef __attribute__((ext_vector_type(8))) short bf16x8;
typedef __attribute__((ext_vector_type(4))) float f32x4;

constexpr int HEADS = 16;
constexpr int NQ    = 4096;
constexpr int NK    = 1024;
constexpr int KB    = 64;        // keys per tile
constexpr int NT    = NK / KB;   // 16 tiles
constexpr int TPB   = 256;
constexpr float EPS = 1e-8f;

// per-(h,kt) image layout in ws
constexpr int IMG_KH = 0;        // 8KB swizzled K-hi LDS image
constexpr int IMG_KL = 8192;     // 8KB swizzled K-lo LDS image
constexpr int IMG_VF = 16384;    // 8KB V fragment stream (PV B operand)
constexpr int IMG_SZ = 24576;

__device__ __forceinline__ ushort bf16_rn(float f) {
    uint u = __float_as_uint(f);
    u += 0x7FFF + ((u >> 16) & 1);
    return (ushort)(u >> 16);
}
__device__ __forceinline__ float bf16_f(ushort h) {
    return __uint_as_float(((uint)h) << 16);
}
// 128B rows, XOR swizzle at 16B granularity
__device__ __forceinline__ int swz(int row, int b) {
    return row * 128 + (b ^ ((row & 7) << 4));
}
__device__ __forceinline__ void load_lds16(const void* g, void* l) {
    __builtin_amdgcn_global_load_lds(
        (const __attribute__((address_space(1))) void*)g,
        (__attribute__((address_space(3))) void*)l, 16, 0, 0);
}

// ---------------- pre-pass: build per-(h,kt) images ----------------
__global__ __launch_bounds__(TPB)
void prepass(const float* __restrict__ kg, const float* __restrict__ vg,
             char* __restrict__ ws)
{
    const int kt = blockIdx.x;
    const int h  = blockIdx.y;
    const int kb = kt * KB;
    char* img = ws + (size_t)(h * NT + kt) * IMG_SZ;
    const int tid = threadIdx.x;

    // K hi/lo swizzled images: element (j,d) chunked as ushort4 (4 d's)
    const float4* k4 = reinterpret_cast<const float4*>(kg);
    #pragma unroll
    for (int i = 0; i < 4; ++i) {
        int fi = i * 256 + tid;
        int j = fi >> 4, dq = fi & 15;
        float4 kv = k4[(size_t)(kb + j) * 256 + h * 16 + dq];
        float kvals[4] = {kv.x, kv.y, kv.z, kv.w};
        ushort4 hi4, lo4;
        ushort* hp = (ushort*)&hi4; ushort* lp = (ushort*)&lo4;
        #pragma unroll
        for (int e = 0; e < 4; ++e) {
            ushort hh = bf16_rn(kvals[e]);
            hp[e] = hh;
            lp[e] = bf16_rn(kvals[e] - bf16_f(hh));
        }
        int addr = swz(j, dq * 8);
        *(ushort4*)(img + IMG_KH + addr) = hi4;
        *(ushort4*)(img + IMG_KL + addr) = lo4;
    }

    // V fragment stream: unit u = (frag f = cc*4+td) * 64 + lane
    // lane (g,c) of frag (cc,td): V[kb + cc*32 + g*8 + e][h*64 + td*16 + c]
    #pragma unroll
    for (int i = 0; i < 2; ++i) {
        int u = i * 256 + tid;
        int f = u >> 6, l = u & 63;
        int cc = f >> 2, td = f & 3;
        int g = l >> 4, c = l & 15;
        ushort4 lo, hi;
        ushort* lp = (ushort*)&lo; ushort* hp = (ushort*)&hi;
        #pragma unroll
        for (int e = 0; e < 4; ++e) {
            lp[e] = bf16_rn(vg[(size_t)(kb + cc * 32 + g * 8 + e) * 1024 + h * 64 + td * 16 + c]);
            hp[e] = bf16_rn(vg[(size_t)(kb + cc * 32 + g * 8 + 4 + e) * 1024 + h * 64 + td * 16 + c]);
        }
        *(ushort4*)(img + IMG_VF + u * 16)     = lo;
        *(ushort4*)(img + IMG_VF + u * 16 + 8) = hi;
    }
}

// ---------------- main kernel ----------------
__global__ __launch_bounds__(TPB, 2)
void ring_attn_mfma2(const float* __restrict__ qg,
                     const char* __restrict__ ws,
                     float* __restrict__ outg)
{
    __shared__ char   Klds[16384];     // [Kh 8KB | Kl 8KB] swizzled images
    __shared__ ushort Pl[4][32 * 64];  // per-wave P: 32 q x 64 k

    const int qblk = blockIdx.x;       // 128 q per block
    const int h    = blockIdx.y;
    const int tid  = threadIdx.x;
    const int w    = tid >> 6;
    const int lane = tid & 63;
    const int g    = lane >> 4;
    const int c    = lane & 15;

    const int qbase = qblk * 128 + w * 32;   // wave covers 32 q (halves A,B)

    // Q fragments, scale 1/8 folded. [half][cc]
    bf16x8 qh[2][2], ql[2][2];
    {
        const float4* q4 = reinterpret_cast<const float4*>(qg);
        #pragma unroll
        for (int H = 0; H < 2; ++H)
            #pragma unroll
            for (int cc = 0; cc < 2; ++cc) {
                int qi = qbase + H * 16 + c;
                int base = (qi * 1024 + h * 64 + cc * 32 + g * 8) >> 2;
                float4 a = q4[base], b = q4[base + 1];
                float vals[8] = {a.x, a.y, a.z, a.w, b.x, b.y, b.z, b.w};
                #pragma unroll
                for (int e = 0; e < 8; ++e) {
                    float x = vals[e] * 0.125f;
                    ushort hi = bf16_rn(x);
                    qh[H][cc][e] = (short)hi;
                    ql[H][cc][e] = (short)bf16_rn(x - bf16_f(hi));
                }
            }
    }

    f32x4 oA[4], oB[4];
    #pragma unroll
    for (int t = 0; t < 4; ++t)
        #pragma unroll
        for (int r = 0; r < 4; ++r) { oA[t][r] = 0.f; oB[t][r] = 0.f; }
    float mA = -INFINITY, mB = -INFINITY, lA = 0.f, lB = 0.f;

    const char* himg = ws + (size_t)h * NT * IMG_SZ;

    #pragma unroll 1
    for (int kt = 0; kt < NT; ++kt) {
        const char* img = himg + (size_t)kt * IMG_SZ;

        // V frags -> registers (bypass LDS). [cc][td]
        bf16x8 vb[2][4];
        #pragma unroll
        for (int f = 0; f < 8; ++f)
            vb[f >> 2][f & 3] = *(const bf16x8*)(img + IMG_VF + (f * 64 + lane) * 16);

        __syncthreads();   // prev tile's K reads done
        // stage K hi+lo (16KB) via global_load_lds; wave w does its 4KB
        #pragma unroll
        for (int i = 0; i < 4; ++i) {
            int off = w * 4096 + i * 1024;
            load_lds16(img + off + lane * 16, Klds + off);
        }
        __syncthreads();   // DMA drained (compiler emits vmcnt(0) at barrier)

        // ---- QK^T (swapped): S[key][q], 6 MFMA per (t,cc)
        f32x4 sA[4], sB[4];
        #pragma unroll
        for (int t = 0; t < 4; ++t)
            #pragma unroll
            for (int r = 0; r < 4; ++r) { sA[t][r] = 0.f; sB[t][r] = 0.f; }
        #pragma unroll
        for (int t = 0; t < 4; ++t) {
            #pragma unroll
            for (int cc = 0; cc < 2; ++cc) {
                int addr = swz(16 * t + c, 64 * cc + 16 * g);
                bf16x8 ah = *(const bf16x8*)(Klds + addr);
                bf16x8 al = *(const bf16x8*)(Klds + 8192 + addr);
                sA[t] = __builtin_amdgcn_mfma_f32_16x16x32_bf16(ah, qh[0][cc], sA[t], 0, 0, 0);
                sA[t] = __builtin_amdgcn_mfma_f32_16x16x32_bf16(al, qh[0][cc], sA[t], 0, 0, 0);
                sA[t] = __builtin_amdgcn_mfma_f32_16x16x32_bf16(ah, ql[0][cc], sA[t], 0, 0, 0);
                sB[t] = __builtin_amdgcn_mfma_f32_16x16x32_bf16(ah, qh[1][cc], sB[t], 0, 0, 0);
                sB[t] = __builtin_amdgcn_mfma_f32_16x16x32_bf16(al, qh[1][cc], sB[t], 0, 0, 0);
                sB[t] = __builtin_amdgcn_mfma_f32_16x16x32_bf16(ah, ql[1][cc], sB[t], 0, 0, 0);
            }
        }
        // lane (g,c): s*[t][r] = S[key=16t+4g+r][q = half_base + c]

        // ---- online softmax + P write, per half
        #pragma unroll
        for (int H = 0; H < 2; ++H) {
            f32x4* s = H ? sB : sA;
            float& m_run = H ? mB : mA;
            float& l_run = H ? lB : lA;
            f32x4* o = H ? oB : oA;

            float tm = -INFINITY;
            #pragma unroll
            for (int t = 0; t < 4; ++t)
                #pragma unroll
                for (int r = 0; r < 4; ++r) tm = fmaxf(tm, s[t][r]);
            tm = fmaxf(tm, __shfl_xor(tm, 16));
            tm = fmaxf(tm, __shfl_xor(tm, 32));
            float m_new = fmaxf(m_run, tm);
            float alpha = __expf(m_run - m_new);
            m_run = m_new;

            float psum = 0.f;
            #pragma unroll
            for (int t = 0; t < 4; ++t) {
                ushort4 pk;
                ushort* pp = (ushort*)&pk;
                #pragma unroll
                for (int r = 0; r < 4; ++r) {
                    float p = __expf(s[t][r] - m_new);
                    ushort pb = bf16_rn(p);
                    pp[r] = pb;
                    psum += bf16_f(pb);
                }
                *(ushort4*)((char*)(&Pl[w][0]) + swz(H * 16 + c, 32 * t + 8 * g)) = pk;
            }
            psum += __shfl_xor(psum, 16);
            psum += __shfl_xor(psum, 32);
            l_run = l_run * alpha + psum;

            float a0 = __shfl(alpha, 4 * g + 0);
            float a1 = __shfl(alpha, 4 * g + 1);
            float a2 = __shfl(alpha, 4 * g + 2);
            float a3 = __shfl(alpha, 4 * g + 3);
            #pragma unroll
            for (int td = 0; td < 4; ++td) {
                o[td][0] *= a0; o[td][1] *= a1;
                o[td][2] *= a2; o[td][3] *= a3;
            }
        }

        // ---- PV: A = P (wave-private LDS), B = vb regs
        #pragma unroll
        for (int cc = 0; cc < 2; ++cc) {
            bf16x8 paA = *(const bf16x8*)((char*)(&Pl[w][0]) + swz(c,      64 * cc + 16 * g));
            bf16x8 paB = *(const bf16x8*)((char*)(&Pl[w][0]) + swz(16 + c, 64 * cc + 16 * g));
            #pragma unroll
            for (int td = 0; td < 4; ++td) {
                oA[td] = __builtin_amdgcn_mfma_f32_16x16x32_bf16(paA, vb[cc][td], oA[td], 0, 0, 0);
                oB[td] = __builtin_amdgcn_mfma_f32_16x16x32_bf16(paB, vb[cc][td], oB[td], 0, 0, 0);
            }
        }
    }

    // ---- epilogue: rows q' = H*16 + 4g+r, cols d = 16td + c
    #pragma unroll
    for (int H = 0; H < 2; ++H) {
        f32x4* o = H ? oB : oA;
        float lr = H ? lB : lA;
        #pragma unroll
        for (int r = 0; r < 4; ++r) {
            float lq  = __shfl(lr, 4 * g + r);
            float inv = 4.f / (4.f * lq + EPS);
            int qrow  = qbase + H * 16 + 4 * g + r;
            #pragma unroll
            for (int td = 0; td < 4; ++td)
                outg[(size_t)qrow * 1024 + h * 64 + 16 * td + c] = o[td][r] * inv;
        }
    }
}

extern "C" void kernel_launch(void* const* d_in, const int* in_sizes, int n_in,
                              void* d_out, int out_size, void* d_ws, size_t ws_size,
                              hipStream_t stream) {
    const float* q = (const float*)d_in[0];
    const float* k = (const float*)d_in[1];
    const float* v = (const float*)d_in[2];
    float* out = (float*)d_out;
    char* ws = (char*)d_ws;   // needs 16*16*24576 = 6 MB

    prepass<<<dim3(NT, HEADS), dim3(TPB), 0, stream>>>(k, v, ws);
    ring_attn_mfma2<<<dim3(NQ / 128, HEADS), dim3(TPB), 0, stream>>>(q, ws, out);
}